// Round 1
// baseline (578.517 us; speedup 1.0000x reference)
//
#include <hip/hip_runtime.h>
#include <hip/hip_bf16.h>

typedef unsigned short u16;
typedef __bf16 bf16x8 __attribute__((ext_vector_type(8)));
typedef float f32x4 __attribute__((ext_vector_type(4)));

#define S_DIM 2048
#define B_DIM 32
#define H_DIM 1024
#define M_DIM (S_DIM * B_DIM)

__device__ __forceinline__ float fast_tanh(float x) {
  // tanh(x) = 1 - 2/(e^{2x}+1); e->inf => 1, e->0 => -1; no NaN
  float e = __expf(2.0f * x);
  return 1.0f - 2.0f * __builtin_amdgcn_rcpf(e + 1.0f);
}

__device__ __forceinline__ void store_bf16x8(u16* dst, float4 f0, float4 f1) {
  union { u16 s[8]; uint4 v; } pk;
  pk.s[0] = __builtin_bit_cast(u16, (__bf16)f0.x);
  pk.s[1] = __builtin_bit_cast(u16, (__bf16)f0.y);
  pk.s[2] = __builtin_bit_cast(u16, (__bf16)f0.z);
  pk.s[3] = __builtin_bit_cast(u16, (__bf16)f0.w);
  pk.s[4] = __builtin_bit_cast(u16, (__bf16)f1.x);
  pk.s[5] = __builtin_bit_cast(u16, (__bf16)f1.y);
  pk.s[6] = __builtin_bit_cast(u16, (__bf16)f1.z);
  pk.s[7] = __builtin_bit_cast(u16, (__bf16)f1.w);
  *(uint4*)dst = pk.v;
}

// Convert W_attn[:, H:2H] (f32, row stride 2H) -> W2 bf16 [H][H] row-major
__global__ void wconv_kernel(const float* __restrict__ W, u16* __restrict__ W2) {
  const int h = blockIdx.x;
  const int t = threadIdx.x; // 256 threads, 4 floats each
  float4 w4 = *(const float4*)(W + (size_t)h * (2 * H_DIM) + H_DIM + t * 4);
  union { u16 s[4]; uint2 v; } pk;
  pk.s[0] = __builtin_bit_cast(u16, (__bf16)w4.x);
  pk.s[1] = __builtin_bit_cast(u16, (__bf16)w4.y);
  pk.s[2] = __builtin_bit_cast(u16, (__bf16)w4.z);
  pk.s[3] = __builtin_bit_cast(u16, (__bf16)w4.w);
  *(uint2*)(W2 + (size_t)h * H_DIM + t * 4) = pk.v;
}

// u[b][h] = dot(hidden[b,:], W_attn[h, 0:H]) + b_attn[h]   (fp32, exact-ish)
__global__ void uprep_kernel(const float* __restrict__ hidden, const float* __restrict__ W,
                             const float* __restrict__ bias, float* __restrict__ u) {
  int t = blockIdx.x * 256 + threadIdx.x;   // 0..131071
  int h = t >> 7;
  int b = (t >> 2) & 31;
  int kq = t & 3;
  const float4* hv = (const float4*)(hidden + (size_t)b * H_DIM) + kq * 64;
  const float4* wv = (const float4*)(W + (size_t)h * (2 * H_DIM)) + kq * 64;
  float acc = 0.f;
  #pragma unroll 4
  for (int i = 0; i < 64; ++i) {
    float4 a = hv[i], w = wv[i];
    acc += a.x * w.x + a.y * w.y + a.z * w.z + a.w * w.w;
  }
  acc += __shfl_xor(acc, 1);
  acc += __shfl_xor(acc, 2);
  if (kq == 0) u[(size_t)b * H_DIM + h] = acc + bias[h];
}

// Main fused GEMM + tanh + v-dot. Block: 64 rows x full N=1024. 512 thr (8 waves 2x4).
// A k-slice (64x64 bf16) LDS double-buffered; B frags direct from global (L2-resident).
__launch_bounds__(512, 2)
__global__ void gemm_kernel(const float* __restrict__ enc, const u16* __restrict__ W2,
                            const float* __restrict__ u, const float* __restrict__ v,
                            float* __restrict__ scores) {
  __shared__ u16 A_s[2][64][72];   // +8 pad -> 2-way banks only
  __shared__ float red_s[4][64];

  const int tid  = threadIdx.x;
  const int lane = tid & 63;
  const int wid  = tid >> 6;
  const int wm   = wid >> 2;   // 0..1  (32-row group)
  const int wn   = wid & 3;    // 0..3  (256-col group)
  const int q    = lane >> 4;  // 0..3
  const int c16  = lane & 15;
  const int m0   = blockIdx.x * 64;

  const int sr = tid >> 3;     // staging row 0..63
  const int sc = tid & 7;      // staging 8-float chunk 0..7

  f32x4 acc[2][16];
  #pragma unroll
  for (int mi = 0; mi < 2; ++mi)
    #pragma unroll
    for (int nf = 0; nf < 16; ++nf) {
      f32x4 z = {0.f, 0.f, 0.f, 0.f};
      acc[mi][nf] = z;
    }

  const float* srow = enc + (size_t)(m0 + sr) * H_DIM + sc * 8;

  { // stage k-step 0
    float4 f0 = *(const float4*)(srow);
    float4 f1 = *(const float4*)(srow + 4);
    store_bf16x8(&A_s[0][sr][sc * 8], f0, f1);
  }
  __syncthreads();

  #pragma unroll 2
  for (int ks = 0; ks < 16; ++ks) {
    const int cur = ks & 1;
    float4 f0, f1;
    if (ks < 15) { // prefetch next A slice into regs (lands during MFMA loop)
      const float* p = srow + (ks + 1) * 64;
      f0 = *(const float4*)(p);
      f1 = *(const float4*)(p + 4);
    }
    bf16x8 a[2][2];
    #pragma unroll
    for (int mi = 0; mi < 2; ++mi)
      #pragma unroll
      for (int kk = 0; kk < 2; ++kk)
        a[mi][kk] = *(const bf16x8*)&A_s[cur][wm * 32 + mi * 16 + c16][kk * 32 + q * 8];

    const u16* wbase = W2 + (size_t)(wn * 256 + c16) * H_DIM + ks * 64 + q * 8;
    #pragma unroll
    for (int nf = 0; nf < 16; ++nf) {
      bf16x8 b0 = *(const bf16x8*)(wbase + (size_t)nf * 16 * H_DIM);
      bf16x8 b1 = *(const bf16x8*)(wbase + (size_t)nf * 16 * H_DIM + 32);
      acc[0][nf] = __builtin_amdgcn_mfma_f32_16x16x32_bf16(a[0][0], b0, acc[0][nf], 0, 0, 0);
      acc[0][nf] = __builtin_amdgcn_mfma_f32_16x16x32_bf16(a[0][1], b1, acc[0][nf], 0, 0, 0);
      acc[1][nf] = __builtin_amdgcn_mfma_f32_16x16x32_bf16(a[1][0], b0, acc[1][nf], 0, 0, 0);
      acc[1][nf] = __builtin_amdgcn_mfma_f32_16x16x32_bf16(a[1][1], b1, acc[1][nf], 0, 0, 0);
    }
    if (ks < 15) store_bf16x8(&A_s[cur ^ 1][sr][sc * 8], f0, f1);
    __syncthreads();
  }

  // Epilogue: x = acc + u[b][h]; rowsum += v[h]*tanh(x); reduce over h
  float rowsum[2][4];
  #pragma unroll
  for (int mi = 0; mi < 2; ++mi)
    #pragma unroll
    for (int r = 0; r < 4; ++r) rowsum[mi][r] = 0.f;

  #pragma unroll
  for (int nf = 0; nf < 16; ++nf) {
    const int h = wn * 256 + nf * 16 + c16;
    const float vh = v[h];
    #pragma unroll
    for (int mi = 0; mi < 2; ++mi) {
      const int b_base = (wm * 32 + mi * 16 + q * 4) & 31; // m0 % 32 == 0
      #pragma unroll
      for (int r = 0; r < 4; ++r) {
        float x = acc[mi][nf][r] + u[(size_t)(b_base + r) * H_DIM + h];
        rowsum[mi][r] += vh * fast_tanh(x);
      }
    }
  }
  #pragma unroll
  for (int mi = 0; mi < 2; ++mi)
    #pragma unroll
    for (int r = 0; r < 4; ++r) {
      float s = rowsum[mi][r];
      s += __shfl_xor(s, 1);
      s += __shfl_xor(s, 2);
      s += __shfl_xor(s, 4);
      s += __shfl_xor(s, 8);
      if (c16 == 0) red_s[wn][wm * 32 + mi * 16 + q * 4 + r] = s;
    }
  __syncthreads();
  if (tid < 64) {
    float s = red_s[0][tid] + red_s[1][tid] + red_s[2][tid] + red_s[3][tid];
    scores[m0 + tid] = s;
  }
}

// softmax over S per batch row b; scores[m] with m = s*B + b; out[b][0][s]
__global__ void softmax_kernel(const float* __restrict__ scores, float* __restrict__ out) {
  const int b = blockIdx.x;
  const int t = threadIdx.x;        // 256
  const int lane = t & 63, wid = t >> 6;
  __shared__ float redm[4], reds[4];
  float loc[8];
  float mx = -3.0e38f;
  #pragma unroll
  for (int i = 0; i < 8; ++i) {
    loc[i] = scores[(size_t)(i * 256 + t) * B_DIM + b];
    mx = fmaxf(mx, loc[i]);
  }
  #pragma unroll
  for (int off = 1; off < 64; off <<= 1) mx = fmaxf(mx, __shfl_xor(mx, off));
  if (lane == 0) redm[wid] = mx;
  __syncthreads();
  mx = fmaxf(fmaxf(redm[0], redm[1]), fmaxf(redm[2], redm[3]));
  float sum = 0.f;
  #pragma unroll
  for (int i = 0; i < 8; ++i) { loc[i] = __expf(loc[i] - mx); sum += loc[i]; }
  #pragma unroll
  for (int off = 1; off < 64; off <<= 1) sum += __shfl_xor(sum, off);
  if (lane == 0) reds[wid] = sum;
  __syncthreads();
  sum = reds[0] + reds[1] + reds[2] + reds[3];
  float inv = 1.0f / sum;
  #pragma unroll
  for (int i = 0; i < 8; ++i) out[(size_t)b * S_DIM + i * 256 + t] = loc[i] * inv;
}

extern "C" void kernel_launch(void* const* d_in, const int* in_sizes, int n_in,
                              void* d_out, int out_size, void* d_ws, size_t ws_size,
                              hipStream_t stream) {
  const float* hidden = (const float*)d_in[0];
  const float* enc    = (const float*)d_in[1];
  const float* W      = (const float*)d_in[2];
  const float* bias   = (const float*)d_in[3];
  const float* v      = (const float*)d_in[4];
  float* out = (float*)d_out;

  char* ws = (char*)d_ws;
  u16*   W2     = (u16*)ws;                                        // 2 MB
  float* u      = (float*)(ws + (2u << 20));                       // 128 KB
  float* scores = (float*)(ws + (2u << 20) + (128u << 10));        // 256 KB

  wconv_kernel<<<H_DIM, 256, 0, stream>>>(W, W2);
  uprep_kernel<<<512, 256, 0, stream>>>(hidden, W, bias, u);
  gemm_kernel<<<M_DIM / 64, 512, 0, stream>>>(enc, W2, u, v, scores);
  softmax_kernel<<<B_DIM, 256, 0, stream>>>(scores, out);
}